// Round 6
// baseline (327.034 us; speedup 1.0000x reference)
//
#include <hip/hip_runtime.h>
#include <hip/hip_cooperative_groups.h>
#include <math.h>

namespace cg = cooperative_groups;

#define QSCALE (0.2886751345948129f * 1.4426950408889634f)  // 1/sqrt(12) * log2(e)

#if __has_builtin(__builtin_amdgcn_exp2f)
#define EXP2F(x) __builtin_amdgcn_exp2f(x)
#else
#define EXP2F(x) exp2f(x)
#endif

typedef __attribute__((ext_vector_type(8))) _Float16 half8;
typedef __attribute__((ext_vector_type(4))) _Float16 half4_t;
typedef __attribute__((ext_vector_type(4))) float floatx4;

#define MFMA32F16(a, b, c) __builtin_amdgcn_mfma_f32_16x16x32_f16((a), (b), (c), 0, 0, 0)
#define MFMA16F16(a, b, c) __builtin_amdgcn_mfma_f32_16x16x16f16((a), (b), (c), 0, 0, 0)

static __device__ inline float bperm(float v, int addr_bytes) {
    return __int_as_float(__builtin_amdgcn_ds_bpermute(addr_bytes, __float_as_int(v)));
}

// ================= Fused cooperative kernel =================
// grid = 512 blocks x 256 threads (2 blocks/CU co-resident).
// Phase P: blk<18 weight swizzle | blk 18..25 mask scan | blk>=32 zero k/v frags
// Phase Q: 2 row-groups/block QKV fp16-split MFMA, shared W double-buffer
// Phase A: MFMA flash attention (round-5 structure, XCD-pinned batches)
__global__ __launch_bounds__(256, 2)
void fused(const float* __restrict__ x, const int* __restrict__ mask,
           const float* __restrict__ Wq, const float* __restrict__ Wk,
           const float* __restrict__ Wv,
           _Float16* __restrict__ wfh, _Float16* __restrict__ wfl,
           int* __restrict__ dst, int* __restrict__ nvalid,
           _Float16* __restrict__ qfh, _Float16* __restrict__ qfl,
           _Float16* __restrict__ kfh, _Float16* __restrict__ kfl,
           _Float16* __restrict__ vtf, float4* __restrict__ zbase,
           float* __restrict__ out)
{
    __shared__ __align__(16) float smem[6144];   // 24 KB, unioned across phases
    cg::grid_group grid = cg::this_grid();
    const int blk  = blockIdx.x;
    const int tid  = threadIdx.x;
    const int lane = tid & 63;
    const int w    = tid >> 6;
    const int m15  = lane & 15;
    const int q8   = lane >> 4;

    // ---------------- Phase P ----------------
    if (blk < 18) {
        // weight swizzle -> fp16 hi/lo B-frags (4608 threads = 18 blocks)
        int t = blk * 256 + tid;
        if (t < 4608) {
            int l2 = t & 63;
            int nt = (t >> 6) % 3;
            int ks = t / 192;
            const float* W = (nt == 0) ? Wq : (nt == 1) ? Wk : Wv;
            const float scale = (nt == 0) ? QSCALE : 1.0f;
            int col = l2 & 15;
            int kq  = l2 >> 4;
            half8 hi, lo;
            #pragma unroll
            for (int j = 0; j < 8; ++j) {
                int dim = ks * 32 + kq * 8 + j;
                float f = (col < 12) ? W[dim * 12 + col] * scale : 0.0f;
                _Float16 h = (_Float16)f;
                hi[j] = h;
                lo[j] = (_Float16)(f - (float)h);
            }
            size_t off = ((size_t)(ks * 3 + nt) * 64 + l2) * 8;
            *(half8*)(wfh + off) = hi;
            *(half8*)(wfl + off) = lo;
        }
    } else if (blk < 26) {
        // per-batch mask scan / compaction
        int* cnt = (int*)smem;
        const int bb = blk - 18;
        const int* mb = mask + bb * 2048;
        int local[8]; int c = 0;
        #pragma unroll
        for (int i = 0; i < 8; ++i) { local[i] = (mb[tid * 8 + i] != 0); c += local[i]; }
        cnt[tid] = c;
        __syncthreads();
        for (int off = 1; off < 256; off <<= 1) {
            int u = cnt[tid];
            int add = (tid >= off) ? cnt[tid - off] : 0;
            __syncthreads();
            cnt[tid] = u + add;
            __syncthreads();
        }
        int run = (tid == 0) ? 0 : cnt[tid - 1];
        int* db = dst + bb * 2048;
        #pragma unroll
        for (int i = 0; i < 8; ++i) { db[tid * 8 + i] = local[i] ? run : -1; run += local[i]; }
        if (tid == 255) nvalid[bb] = cnt[255];
    } else if (blk >= 32) {
        // zero kfh/kfl/vtf (2.5 MB = 163840 float4) across 480 blocks
        const float4 z = make_float4(0.f, 0.f, 0.f, 0.f);
        for (int i = (blk - 32) * 256 + tid; i < 163840; i += 480 * 256) zbase[i] = z;
    }
    __threadfence();
    grid.sync();

    // ---------------- Phase Q: QKV projection ----------------
    {
        const int g0 = blk * 2;
        const float* xb0 = x + (size_t)(g0 * 16 + m15) * 768 + q8 * 8;
        const float* xb1 = xb0 + 16 * 768;
        const half8* WH = (const half8*)wfh;
        const half8* WL = (const half8*)wfl;

        // issue all 24 x loads up front
        float xv0[6][8], xv1[6][8];
        #pragma unroll
        for (int s = 0; s < 6; ++s) {
            const int ks = w * 6 + s;
            *(float4*)(xv0[s])     = *(const float4*)(xb0 + ks * 32);
            *(float4*)(xv0[s] + 4) = *(const float4*)(xb0 + ks * 32 + 4);
            *(float4*)(xv1[s])     = *(const float4*)(xb1 + ks * 32);
            *(float4*)(xv1[s] + 4) = *(const float4*)(xb1 + ks * 32 + 4);
        }

        floatx4 acc[2][3];
        #pragma unroll
        for (int gi = 0; gi < 2; ++gi)
            #pragma unroll
            for (int n = 0; n < 3; ++n) acc[gi][n] = (floatx4){0.f, 0.f, 0.f, 0.f};

        half8 bh[2][3], bl[2][3];
        {
            const int ks = w * 6;
            #pragma unroll
            for (int n = 0; n < 3; ++n) {
                bh[0][n] = WH[(ks * 3 + n) * 64 + lane];
                bl[0][n] = WL[(ks * 3 + n) * 64 + lane];
            }
        }

        #pragma unroll
        for (int s = 0; s < 6; ++s) {
            const int cur = s & 1, nxt = cur ^ 1;
            if (s < 5) {
                const int ksn = w * 6 + s + 1;
                #pragma unroll
                for (int n = 0; n < 3; ++n) {
                    bh[nxt][n] = WH[(ksn * 3 + n) * 64 + lane];
                    bl[nxt][n] = WL[(ksn * 3 + n) * 64 + lane];
                }
            }
            half8 ah0, al0, ah1, al1;
            #pragma unroll
            for (int j = 0; j < 8; ++j) {
                _Float16 h0 = (_Float16)xv0[s][j];
                ah0[j] = h0;
                al0[j] = (_Float16)(xv0[s][j] - (float)h0);
                _Float16 h1 = (_Float16)xv1[s][j];
                ah1[j] = h1;
                al1[j] = (_Float16)(xv1[s][j] - (float)h1);
            }
            #pragma unroll
            for (int n = 0; n < 3; ++n) {
                acc[0][n] = MFMA32F16(ah0, bh[cur][n], acc[0][n]);
                acc[1][n] = MFMA32F16(ah1, bh[cur][n], acc[1][n]);
            }
            #pragma unroll
            for (int n = 0; n < 3; ++n) {
                acc[0][n] = MFMA32F16(al0, bh[cur][n], acc[0][n]);
                acc[1][n] = MFMA32F16(al1, bh[cur][n], acc[1][n]);
            }
            #pragma unroll
            for (int n = 0; n < 3; ++n) {
                acc[0][n] = MFMA32F16(ah0, bl[cur][n], acc[0][n]);
                acc[1][n] = MFMA32F16(ah1, bl[cur][n], acc[1][n]);
            }
        }

        // cross-wave combine: smem[((gi*4+w)*3+n)*64+lane] (float4 slots)
        #pragma unroll
        for (int gi = 0; gi < 2; ++gi)
            #pragma unroll
            for (int n = 0; n < 3; ++n)
                *(floatx4*)(smem + (((gi * 4 + w) * 3 + n) * 64 + lane) * 4) = acc[gi][n];
        __syncthreads();
        if (w < 3) {
            #pragma unroll
            for (int gi = 0; gi < 2; ++gi) {
                floatx4 tot = (floatx4){0.f, 0.f, 0.f, 0.f};
                #pragma unroll
                for (int w2 = 0; w2 < 4; ++w2) {
                    floatx4 t = *(const floatx4*)(smem + (((gi * 4 + w2) * 3 + w) * 64 + lane) * 4);
                    tot.x += t.x; tot.y += t.y; tot.z += t.z; tot.w += t.w;
                }
                const int g   = g0 + gi;
                const int col = m15;
                const int r0  = q8 * 4;
                #pragma unroll
                for (int r = 0; r < 4; ++r) {
                    const int row = g * 16 + r0 + r;
                    const float val = tot[r];
                    if (w == 0) {                  // Q -> B-frag, hi/lo
                        if (col < 12) {
                            size_t off = ((size_t)g * 64 + (col >> 3) * 16 + (r0 + r)) * 8 + (col & 7);
                            _Float16 h = (_Float16)val;
                            qfh[off] = h;
                            qfl[off] = (_Float16)(val - (float)h);
                        }
                    } else {
                        const int d = dst[row];
                        if (d >= 0) {
                            const int bb = row >> 11;
                            if (w == 1) {          // K -> A-frag, hi/lo (compacted)
                                if (col < 12) {
                                    size_t off = (((size_t)(bb * 128 + (d >> 4))) * 64
                                                  + (col >> 3) * 16 + (d & 15)) * 8 + (col & 7);
                                    _Float16 h = (_Float16)val;
                                    kfh[off] = h;
                                    kfl[off] = (_Float16)(val - (float)h);
                                }
                            } else {               // V^T -> A-frag + ones row (l)
                                if (col < 12) {
                                    size_t off = (((size_t)(bb * 128 + (d >> 4))) * 64
                                                  + ((d & 15) >> 2) * 16 + col) * 4 + (d & 3);
                                    vtf[off] = (_Float16)val;
                                } else if (col == 12) {
                                    size_t off = (((size_t)(bb * 128 + (d >> 4))) * 64
                                                  + ((d & 15) >> 2) * 16 + 12) * 4 + (d & 3);
                                    vtf[off] = (_Float16)1.0f;
                                }
                            }
                        }
                    }
                }
            }
        }
    }
    __threadfence();
    grid.sync();

    // ---------------- Phase A: flash attention ----------------
    {
        float* cm = smem;                    // 512 floats
        floatx4* co = (floatx4*)(smem + 512);  // 512 float4
        const int bb = blk & 7;              // XCD-pinned batch
        const int gl = blk >> 3;             // 0..63 within batch
        const int g0 = bb * 128 + gl * 2;

        const half8 qh0 = *(const half8*)(qfh + ((size_t)g0 * 64 + lane) * 8);
        const half8 ql0 = *(const half8*)(qfl + ((size_t)g0 * 64 + lane) * 8);
        const half8 qh1 = *(const half8*)(qfh + ((size_t)(g0 + 1) * 64 + lane) * 8);
        const half8 ql1 = *(const half8*)(qfl + ((size_t)(g0 + 1) * 64 + lane) * 8);

        const half8* KH = (const half8*)kfh + (size_t)bb * 128 * 64;
        const half8* KL = (const half8*)kfl + (size_t)bb * 128 * 64;
        const half4_t* VT = (const half4_t*)vtf + (size_t)bb * 128 * 64;

        const int nv = nvalid[bb];
        const int nt = (nv + 15) >> 4;
        const int a16 = (lane ^ 16) << 2;
        const int a32 = (lane ^ 32) << 2;

        float m0 = -INFINITY, m1 = -INFINITY;
        floatx4 o0 = {0.f, 0.f, 0.f, 0.f};
        floatx4 o1 = o0;

        int t = w;
        half8 kh, kl;
        half4_t va;
        if (t < nt) {
            kh = KH[t * 64 + lane];
            kl = KL[t * 64 + lane];
            va = VT[t * 64 + lane];
        }
        for (; t < nt; t += 4) {
            half8 nkh, nkl; half4_t nva;
            if (t + 4 < nt) {
                nkh = KH[(t + 4) * 64 + lane];
                nkl = KL[(t + 4) * 64 + lane];
                nva = VT[(t + 4) * 64 + lane];
            }
            floatx4 s0 = {0.f, 0.f, 0.f, 0.f};
            floatx4 s1 = s0;
            s0 = MFMA32F16(kh, qh0, s0);
            s1 = MFMA32F16(kh, qh1, s1);
            s0 = MFMA32F16(kl, qh0, s0);
            s1 = MFMA32F16(kl, qh1, s1);
            s0 = MFMA32F16(kh, ql0, s0);
            s1 = MFMA32F16(kh, ql1, s1);
            {
                float pm = fmaxf(fmaxf(s0.x, s0.y), fmaxf(s0.z, s0.w));
                pm = fmaxf(pm, bperm(pm, a16));
                pm = fmaxf(pm, bperm(pm, a32));
                float mnew = fmaxf(m0, pm);
                float corr = EXP2F(m0 - mnew);
                o0.x *= corr; o0.y *= corr; o0.z *= corr; o0.w *= corr;
                half4_t pb;
                pb[0] = (_Float16)EXP2F(s0.x - mnew);
                pb[1] = (_Float16)EXP2F(s0.y - mnew);
                pb[2] = (_Float16)EXP2F(s0.z - mnew);
                pb[3] = (_Float16)EXP2F(s0.w - mnew);
                o0 = MFMA16F16(va, pb, o0);
                m0 = mnew;
            }
            {
                float pm = fmaxf(fmaxf(s1.x, s1.y), fmaxf(s1.z, s1.w));
                pm = fmaxf(pm, bperm(pm, a16));
                pm = fmaxf(pm, bperm(pm, a32));
                float mnew = fmaxf(m1, pm);
                float corr = EXP2F(m1 - mnew);
                o1.x *= corr; o1.y *= corr; o1.z *= corr; o1.w *= corr;
                half4_t pb;
                pb[0] = (_Float16)EXP2F(s1.x - mnew);
                pb[1] = (_Float16)EXP2F(s1.y - mnew);
                pb[2] = (_Float16)EXP2F(s1.z - mnew);
                pb[3] = (_Float16)EXP2F(s1.w - mnew);
                o1 = MFMA16F16(va, pb, o1);
                m1 = mnew;
            }
            kh = nkh; kl = nkl; va = nva;
        }

        __syncthreads();                     // smem was read in phase Q epilogue
        cm[(0 * 4 + w) * 64 + lane] = m0;
        cm[(1 * 4 + w) * 64 + lane] = m1;
        co[(0 * 4 + w) * 64 + lane] = o0;
        co[(1 * 4 + w) * 64 + lane] = o1;
        __syncthreads();
        if (w < 2) {
            const int gi = w;
            float gm = -INFINITY;
            #pragma unroll
            for (int w2 = 0; w2 < 4; ++w2) gm = fmaxf(gm, cm[(gi * 4 + w2) * 64 + lane]);
            floatx4 O = {0.f, 0.f, 0.f, 0.f};
            #pragma unroll
            for (int w2 = 0; w2 < 4; ++w2) {
                float f = EXP2F(cm[(gi * 4 + w2) * 64 + lane] - gm);
                floatx4 ow = co[(gi * 4 + w2) * 64 + lane];
                O.x += ow.x * f; O.y += ow.y * f; O.z += ow.z * f; O.w += ow.w * f;
            }
            float L = bperm(O.x, (48 + m15) << 2);   // l at C row 12
            float inv = 1.0f / L;
            if ((lane >> 4) < 3) {
                float4 ov = make_float4(O.x * inv, O.y * inv, O.z * inv, O.w * inv);
                *(float4*)(out + ((size_t)(g0 + gi) * 16 + m15) * 12 + (lane >> 4) * 4) = ov;
            }
        }
    }
}

extern "C" void kernel_launch(void* const* d_in, const int* in_sizes, int n_in,
                              void* d_out, int out_size, void* d_ws, size_t ws_size,
                              hipStream_t stream) {
    const float* x    = (const float*)d_in[0];
    const int*   mask = (const int*)  d_in[1];
    const float* Wk   = (const float*)d_in[2];   // key_weight
    const float* Wq   = (const float*)d_in[3];   // query_weight
    const float* Wv   = (const float*)d_in[4];   // value_weight
    float* out = (float*)d_out;

    char* base = (char*)d_ws;
    _Float16* qfh = (_Float16*)(base);                    // 1 MB
    _Float16* qfl = (_Float16*)(base + (1u << 20));       // 1 MB
    _Float16* kfh = (_Float16*)(base + (2u << 20));       // 1 MB
    _Float16* kfl = (_Float16*)(base + (3u << 20));       // 1 MB
    _Float16* vtf = (_Float16*)(base + (4u << 20));       // 0.5 MB
    _Float16* wfh = (_Float16*)(base + 4718592);          // 73728 B
    _Float16* wfl = (_Float16*)(base + 4718592 + 73728);  // 73728 B
    int* dst      = (int*)(base + 4866048);               // 64 KB
    int* nvalid   = (int*)(base + 4866048 + 65536);       // 32 B
    float4* zbase = (float4*)(base + (2u << 20));         // zero [2MB, 4.5MB)

    void* args[16] = {
        (void*)&x, (void*)&mask, (void*)&Wq, (void*)&Wk, (void*)&Wv,
        (void*)&wfh, (void*)&wfl, (void*)&dst, (void*)&nvalid,
        (void*)&qfh, (void*)&qfl, (void*)&kfh, (void*)&kfl, (void*)&vtf,
        (void*)&zbase, (void*)&out
    };
    hipLaunchCooperativeKernel((const void*)fused, dim3(512), dim3(256), args, 0, stream);
}

// Round 7
// 124.158 us; speedup vs baseline: 2.6340x; 2.6340x over previous
//
#include <hip/hip_runtime.h>
#include <math.h>

#define QSCALE (0.2886751345948129f * 1.4426950408889634f)  // 1/sqrt(12) * log2(e)

#if __has_builtin(__builtin_amdgcn_exp2f)
#define EXP2F(x) __builtin_amdgcn_exp2f(x)
#else
#define EXP2F(x) exp2f(x)
#endif

typedef __attribute__((ext_vector_type(8))) _Float16 half8;
typedef __attribute__((ext_vector_type(4))) _Float16 half4_t;
typedef __attribute__((ext_vector_type(4))) float floatx4;

#define MFMA32F16(a, b, c) __builtin_amdgcn_mfma_f32_16x16x32_f16((a), (b), (c), 0, 0, 0)
#define MFMA16F16(a, b, c) __builtin_amdgcn_mfma_f32_16x16x16f16((a), (b), (c), 0, 0, 0)

static __device__ inline float bperm(float v, int addr_bytes) {
    return __int_as_float(__builtin_amdgcn_ds_bpermute(addr_bytes, __float_as_int(v)));
}

// ---------------- Kernel P: weight swizzle -> fp16 hi/lo B-frags -----------
__global__ __launch_bounds__(256)
void prep(const float* __restrict__ Wq, const float* __restrict__ Wk,
          const float* __restrict__ Wv, _Float16* __restrict__ wfh,
          _Float16* __restrict__ wfl)
{
    int t = blockIdx.x * 256 + threadIdx.x;
    if (t >= 4608) return;                 // 24 ks * 3 nt * 64 lanes
    int lane = t & 63;
    int nt   = (t >> 6) % 3;
    int ks   = t / 192;
    const float* W = (nt == 0) ? Wq : (nt == 1) ? Wk : Wv;
    const float scale = (nt == 0) ? QSCALE : 1.0f;
    int col = lane & 15;
    int kq  = lane >> 4;
    half8 hi, lo;
    #pragma unroll
    for (int j = 0; j < 8; ++j) {
        int dim = ks * 32 + kq * 8 + j;
        float f = (col < 12) ? W[dim * 12 + col] * scale : 0.0f;
        _Float16 h = (_Float16)f;
        hi[j] = h;
        lo[j] = (_Float16)(f - (float)h);
    }
    size_t off = ((size_t)(ks * 3 + nt) * 64 + lane) * 8;
    *(half8*)(wfh + off) = hi;
    *(half8*)(wfl + off) = lo;
}

// ---------------- Kernel 1: QKV projection, fp16-split MFMA ----------------
// grid=1024 (16 rows/block), block=256 (4 waves split K: 6 x 32-dim steps).
// A-frags direct from global (16B/lane x 4 q8-lanes = full 64B lines, no
// overfetch — verified round 6 FETCH). Epilogue writes COMPLETE fragment
// coverage: masked keys get k=0 / v=0 / ones=0 (self-masking in attention),
// K-frag h>=12 lanes zeroed, V^T rows 13..15 zeroed, row 12 = mask (for l).
__global__ __launch_bounds__(256, 3)
void qkv_mfma(const float* __restrict__ x, const _Float16* __restrict__ wfh,
              const _Float16* __restrict__ wfl, const int* __restrict__ mask,
              _Float16* __restrict__ qfh, _Float16* __restrict__ qfl,
              _Float16* __restrict__ kfh, _Float16* __restrict__ kfl,
              _Float16* __restrict__ vtf)
{
    __shared__ __align__(16) float cbuf[3072];   // [w][nt][lane][4]
    const int tid  = threadIdx.x;
    const int lane = tid & 63;
    const int w    = tid >> 6;
    const int g    = blockIdx.x;
    const int rowbase = g * 16;
    const int m15 = lane & 15;
    const int q8  = lane >> 4;

    const float* xbase = x + (size_t)(rowbase + m15) * 768 + q8 * 8;
    const half8* WH = (const half8*)wfh;
    const half8* WL = (const half8*)wfl;

    // issue ALL x loads up front (independent, 12 in flight)
    float xv[6][8];
    #pragma unroll
    for (int s = 0; s < 6; ++s) {
        const int ks = w * 6 + s;
        *(float4*)(xv[s])     = *(const float4*)(xbase + ks * 32);
        *(float4*)(xv[s] + 4) = *(const float4*)(xbase + ks * 32 + 4);
    }

    floatx4 acc0 = {0.f, 0.f, 0.f, 0.f};
    floatx4 acc1 = acc0, acc2 = acc0;

    half8 bh[2][3], bl[2][3];
    {
        const int ks = w * 6;
        #pragma unroll
        for (int n = 0; n < 3; ++n) {
            bh[0][n] = WH[(ks * 3 + n) * 64 + lane];
            bl[0][n] = WL[(ks * 3 + n) * 64 + lane];
        }
    }

    #pragma unroll
    for (int s = 0; s < 6; ++s) {
        const int cur = s & 1, nxt = cur ^ 1;
        if (s < 5) {
            const int ksn = w * 6 + s + 1;
            #pragma unroll
            for (int n = 0; n < 3; ++n) {
                bh[nxt][n] = WH[(ksn * 3 + n) * 64 + lane];
                bl[nxt][n] = WL[(ksn * 3 + n) * 64 + lane];
            }
        }
        half8 ah, al;
        #pragma unroll
        for (int j = 0; j < 8; ++j) {
            _Float16 h = (_Float16)xv[s][j];
            ah[j] = h;
            al[j] = (_Float16)(xv[s][j] - (float)h);
        }
        acc0 = MFMA32F16(ah, bh[cur][0], acc0);
        acc1 = MFMA32F16(ah, bh[cur][1], acc1);
        acc2 = MFMA32F16(ah, bh[cur][2], acc2);
        acc0 = MFMA32F16(al, bh[cur][0], acc0);
        acc1 = MFMA32F16(al, bh[cur][1], acc1);
        acc2 = MFMA32F16(al, bh[cur][2], acc2);
        acc0 = MFMA32F16(ah, bl[cur][0], acc0);
        acc1 = MFMA32F16(ah, bl[cur][1], acc1);
        acc2 = MFMA32F16(ah, bl[cur][2], acc2);
    }

    *(floatx4*)(cbuf + ((w * 3 + 0) * 64 + lane) * 4) = acc0;
    *(floatx4*)(cbuf + ((w * 3 + 1) * 64 + lane) * 4) = acc1;
    *(floatx4*)(cbuf + ((w * 3 + 2) * 64 + lane) * 4) = acc2;
    __syncthreads();
    if (w < 3) {
        floatx4 t0 = *(const floatx4*)(cbuf + ((0 * 3 + w) * 64 + lane) * 4);
        floatx4 t1 = *(const floatx4*)(cbuf + ((1 * 3 + w) * 64 + lane) * 4);
        floatx4 t2 = *(const floatx4*)(cbuf + ((2 * 3 + w) * 64 + lane) * 4);
        floatx4 t3 = *(const floatx4*)(cbuf + ((3 * 3 + w) * 64 + lane) * 4);
        floatx4 tot = t0 + t1 + t2 + t3;
        const int col = m15;
        const int r0  = q8 * 4;
        #pragma unroll
        for (int r = 0; r < 4; ++r) {
            const int row = rowbase + r0 + r;
            const float val = tot[r];
            if (w == 0) {                  // Q -> B-frag layout, hi/lo
                if (col < 12) {
                    size_t off = ((size_t)g * 64 + (col >> 3) * 16 + (r0 + r)) * 8 + (col & 7);
                    _Float16 h = (_Float16)val;
                    qfh[off] = h;
                    qfl[off] = (_Float16)(val - (float)h);
                }
            } else {
                const int d   = row & 2047;        // raw slot, no compaction
                const int bb  = row >> 11;
                const int msk = mask[row];
                const size_t tb = ((size_t)(bb * 128 + (d >> 4))) * 64;
                if (w == 1) {              // K -> A-frag, zero-masked, h>=12 zero
                    float vv = (msk && col < 12) ? val : 0.f;
                    _Float16 h  = (_Float16)vv;
                    _Float16 lo = (_Float16)(vv - (float)h);
                    size_t off1 = (tb + (col >> 3) * 16 + (d & 15)) * 8 + (col & 7);
                    size_t off2 = (tb + ((col >> 3) + 2) * 16 + (d & 15)) * 8 + (col & 7);
                    kfh[off1] = h;
                    kfl[off1] = lo;
                    kfh[off2] = (_Float16)0.f;
                    kfl[off2] = (_Float16)0.f;
                } else {                   // V^T -> A-frag; row12 = mask (l), 13-15 = 0
                    float vv;
                    if (col < 12)       vv = msk ? val : 0.f;
                    else if (col == 12) vv = msk ? 1.f : 0.f;
                    else                vv = 0.f;
                    size_t off = (tb + ((d & 15) >> 2) * 16 + col) * 4 + (d & 3);
                    vtf[off] = (_Float16)vv;
                }
            }
        }
    }
}

// ---------------- Kernel 2: MFMA flash attention ---------------------------
// grid=512 (two 16-row q-groups per block), block=256 (4 waves stride-4 over
// a fixed 128 16-key tiles). XCD swizzle: batch = blockIdx&7. Masked keys
// self-mask (k=0 -> s=0 < true max; v=ones=0 -> zero contribution).
__global__ __launch_bounds__(256)
void attn(const _Float16* __restrict__ qfh, const _Float16* __restrict__ qfl,
          const _Float16* __restrict__ kfh, const _Float16* __restrict__ kfl,
          const _Float16* __restrict__ vtf, float* __restrict__ out)
{
    __shared__ float cm[512];
    __shared__ __align__(16) floatx4 co[512];
    const int tid  = threadIdx.x;
    const int lane = tid & 63;
    const int w    = tid >> 6;
    const int bb   = blockIdx.x & 7;       // XCD-pinned batch
    const int gl   = blockIdx.x >> 3;      // 0..63 within batch
    const int g0   = bb * 128 + gl * 2;
    const int m15  = lane & 15;

    const half8 qh0 = *(const half8*)(qfh + ((size_t)g0 * 64 + lane) * 8);
    const half8 ql0 = *(const half8*)(qfl + ((size_t)g0 * 64 + lane) * 8);
    const half8 qh1 = *(const half8*)(qfh + ((size_t)(g0 + 1) * 64 + lane) * 8);
    const half8 ql1 = *(const half8*)(qfl + ((size_t)(g0 + 1) * 64 + lane) * 8);

    const half8* KH = (const half8*)kfh + (size_t)bb * 128 * 64;
    const half8* KL = (const half8*)kfl + (size_t)bb * 128 * 64;
    const half4_t* VT = (const half4_t*)vtf + (size_t)bb * 128 * 64;

    const int a16 = (lane ^ 16) << 2;
    const int a32 = (lane ^ 32) << 2;

    float m0 = -INFINITY, m1 = -INFINITY;
    floatx4 o0 = {0.f, 0.f, 0.f, 0.f};
    floatx4 o1 = o0;

    int t = w;
    half8 kh = KH[t * 64 + lane];
    half8 kl = KL[t * 64 + lane];
    half4_t va = VT[t * 64 + lane];
    for (; t < 128; t += 4) {
        half8 nkh, nkl; half4_t nva;
        if (t + 4 < 128) {
            nkh = KH[(t + 4) * 64 + lane];
            nkl = KL[(t + 4) * 64 + lane];
            nva = VT[(t + 4) * 64 + lane];
        }
        floatx4 s0 = {0.f, 0.f, 0.f, 0.f};
        floatx4 s1 = s0;
        s0 = MFMA32F16(kh, qh0, s0);
        s1 = MFMA32F16(kh, qh1, s1);
        s0 = MFMA32F16(kl, qh0, s0);
        s1 = MFMA32F16(kl, qh1, s1);
        s0 = MFMA32F16(kh, ql0, s0);
        s1 = MFMA32F16(kh, ql1, s1);
        {
            float pm = fmaxf(fmaxf(s0.x, s0.y), fmaxf(s0.z, s0.w));
            pm = fmaxf(pm, bperm(pm, a16));
            pm = fmaxf(pm, bperm(pm, a32));
            float mnew = fmaxf(m0, pm);
            float corr = EXP2F(m0 - mnew);
            o0.x *= corr; o0.y *= corr; o0.z *= corr; o0.w *= corr;
            half4_t pb;
            pb[0] = (_Float16)EXP2F(s0.x - mnew);
            pb[1] = (_Float16)EXP2F(s0.y - mnew);
            pb[2] = (_Float16)EXP2F(s0.z - mnew);
            pb[3] = (_Float16)EXP2F(s0.w - mnew);
            o0 = MFMA16F16(va, pb, o0);
            m0 = mnew;
        }
        {
            float pm = fmaxf(fmaxf(s1.x, s1.y), fmaxf(s1.z, s1.w));
            pm = fmaxf(pm, bperm(pm, a16));
            pm = fmaxf(pm, bperm(pm, a32));
            float mnew = fmaxf(m1, pm);
            float corr = EXP2F(m1 - mnew);
            o1.x *= corr; o1.y *= corr; o1.z *= corr; o1.w *= corr;
            half4_t pb;
            pb[0] = (_Float16)EXP2F(s1.x - mnew);
            pb[1] = (_Float16)EXP2F(s1.y - mnew);
            pb[2] = (_Float16)EXP2F(s1.z - mnew);
            pb[3] = (_Float16)EXP2F(s1.w - mnew);
            o1 = MFMA16F16(va, pb, o1);
            m1 = mnew;
        }
        kh = nkh; kl = nkl; va = nva;
    }

    cm[(0 * 4 + w) * 64 + lane] = m0;
    cm[(1 * 4 + w) * 64 + lane] = m1;
    co[(0 * 4 + w) * 64 + lane] = o0;
    co[(1 * 4 + w) * 64 + lane] = o1;
    __syncthreads();
    if (w < 2) {
        const int gi = w;
        float gm = -INFINITY;
        #pragma unroll
        for (int w2 = 0; w2 < 4; ++w2) gm = fmaxf(gm, cm[(gi * 4 + w2) * 64 + lane]);
        floatx4 O = {0.f, 0.f, 0.f, 0.f};
        #pragma unroll
        for (int w2 = 0; w2 < 4; ++w2) {
            float f = EXP2F(cm[(gi * 4 + w2) * 64 + lane] - gm);
            floatx4 ow = co[(gi * 4 + w2) * 64 + lane];
            O.x += ow.x * f; O.y += ow.y * f; O.z += ow.z * f; O.w += ow.w * f;
        }
        float L = bperm(O.x, (48 + m15) << 2);   // l at C row 12
        float inv = 1.0f / L;
        if ((lane >> 4) < 3) {
            float4 ov = make_float4(O.x * inv, O.y * inv, O.z * inv, O.w * inv);
            *(float4*)(out + ((size_t)(g0 + gi) * 16 + m15) * 12 + (lane >> 4) * 4) = ov;
        }
    }
}

extern "C" void kernel_launch(void* const* d_in, const int* in_sizes, int n_in,
                              void* d_out, int out_size, void* d_ws, size_t ws_size,
                              hipStream_t stream) {
    const float* x    = (const float*)d_in[0];
    const int*   mask = (const int*)  d_in[1];
    const float* Wk   = (const float*)d_in[2];   // key_weight
    const float* Wq   = (const float*)d_in[3];   // query_weight
    const float* Wv   = (const float*)d_in[4];   // value_weight
    float* out = (float*)d_out;

    char* base = (char*)d_ws;
    _Float16* qfh = (_Float16*)(base);                    // 1 MB
    _Float16* qfl = (_Float16*)(base + (1u << 20));       // 1 MB
    _Float16* kfh = (_Float16*)(base + (2u << 20));       // 1 MB
    _Float16* kfl = (_Float16*)(base + (3u << 20));       // 1 MB
    _Float16* vtf = (_Float16*)(base + (4u << 20));       // 0.5 MB
    _Float16* wfh = (_Float16*)(base + 4718592);          // 73728 B
    _Float16* wfl = (_Float16*)(base + 4718592 + 73728);  // 73728 B

    prep<<<18, 256, 0, stream>>>(Wq, Wk, Wv, wfh, wfl);
    qkv_mfma<<<1024, 256, 0, stream>>>(x, wfh, wfl, mask, qfh, qfl, kfh, kfl, vtf);
    attn<<<512, 256, 0, stream>>>(qfh, qfl, kfh, kfl, vtf, out);
}

// Round 8
// 122.198 us; speedup vs baseline: 2.6763x; 1.0160x over previous
//
#include <hip/hip_runtime.h>
#include <math.h>

#define QSCALE (0.2886751345948129f * 1.4426950408889634f)  // 1/sqrt(12) * log2(e)

#if __has_builtin(__builtin_amdgcn_exp2f)
#define EXP2F(x) __builtin_amdgcn_exp2f(x)
#else
#define EXP2F(x) exp2f(x)
#endif

typedef __attribute__((ext_vector_type(8))) _Float16 half8;
typedef __attribute__((ext_vector_type(4))) _Float16 half4_t;
typedef __attribute__((ext_vector_type(4))) float floatx4;

#define MFMA32F16(a, b, c) __builtin_amdgcn_mfma_f32_16x16x32_f16((a), (b), (c), 0, 0, 0)
#define MFMA16F16(a, b, c) __builtin_amdgcn_mfma_f32_16x16x16f16((a), (b), (c), 0, 0, 0)

static __device__ inline float bperm(float v, int addr_bytes) {
    return __int_as_float(__builtin_amdgcn_ds_bpermute(addr_bytes, __float_as_int(v)));
}

// ---------------- Kernel P: weight swizzle -> fp16 hi/lo B-frags -----------
__global__ __launch_bounds__(256)
void prep(const float* __restrict__ Wq, const float* __restrict__ Wk,
          const float* __restrict__ Wv, _Float16* __restrict__ wfh,
          _Float16* __restrict__ wfl)
{
    int t = blockIdx.x * 256 + threadIdx.x;
    if (t >= 4608) return;                 // 24 ks * 3 nt * 64 lanes
    int lane = t & 63;
    int nt   = (t >> 6) % 3;
    int ks   = t / 192;
    const float* W = (nt == 0) ? Wq : (nt == 1) ? Wk : Wv;
    const float scale = (nt == 0) ? QSCALE : 1.0f;
    int col = lane & 15;
    int kq  = lane >> 4;
    half8 hi, lo;
    #pragma unroll
    for (int j = 0; j < 8; ++j) {
        int dim = ks * 32 + kq * 8 + j;
        float f = (col < 12) ? W[dim * 12 + col] * scale : 0.0f;
        _Float16 h = (_Float16)f;
        hi[j] = h;
        lo[j] = (_Float16)(f - (float)h);
    }
    size_t off = ((size_t)(ks * 3 + nt) * 64 + lane) * 8;
    *(half8*)(wfh + off) = hi;
    *(half8*)(wfl + off) = lo;
}

// ---------------- Kernel 1: QKV projection, fp16-split MFMA ----------------
// grid=1024 (16 rows/block), block=256. Main loop identical to round 7.
// NEW epilogue: each block owns exactly one Q/K/V fragment tile -> assemble
// tiles in LDS (zero-init + ds_write_b16 scatter), then 5 coalesced 64-lane
// global stores per block instead of ~1400 scattered 2-byte stores.
__global__ __launch_bounds__(256, 3)
void qkv_mfma(const float* __restrict__ x, const _Float16* __restrict__ wfh,
              const _Float16* __restrict__ wfl, const int* __restrict__ mask,
              _Float16* __restrict__ qfh, _Float16* __restrict__ qfl,
              _Float16* __restrict__ kfh, _Float16* __restrict__ kfl,
              _Float16* __restrict__ vtf)
{
    __shared__ __align__(16) float smem[3072];   // 12 KB: cbuf, then frag tiles
    const int tid  = threadIdx.x;
    const int lane = tid & 63;
    const int w    = tid >> 6;
    const int g    = blockIdx.x;
    const int rowbase = g * 16;
    const int m15 = lane & 15;
    const int q8  = lane >> 4;

    const float* xbase = x + (size_t)(rowbase + m15) * 768 + q8 * 8;
    const half8* WH = (const half8*)wfh;
    const half8* WL = (const half8*)wfl;

    // issue ALL x loads up front (independent, 12 in flight)
    float xv[6][8];
    #pragma unroll
    for (int s = 0; s < 6; ++s) {
        const int ks = w * 6 + s;
        *(float4*)(xv[s])     = *(const float4*)(xbase + ks * 32);
        *(float4*)(xv[s] + 4) = *(const float4*)(xbase + ks * 32 + 4);
    }

    floatx4 acc0 = {0.f, 0.f, 0.f, 0.f};
    floatx4 acc1 = acc0, acc2 = acc0;

    half8 bh[2][3], bl[2][3];
    {
        const int ks = w * 6;
        #pragma unroll
        for (int n = 0; n < 3; ++n) {
            bh[0][n] = WH[(ks * 3 + n) * 64 + lane];
            bl[0][n] = WL[(ks * 3 + n) * 64 + lane];
        }
    }

    #pragma unroll
    for (int s = 0; s < 6; ++s) {
        const int cur = s & 1, nxt = cur ^ 1;
        if (s < 5) {
            const int ksn = w * 6 + s + 1;
            #pragma unroll
            for (int n = 0; n < 3; ++n) {
                bh[nxt][n] = WH[(ksn * 3 + n) * 64 + lane];
                bl[nxt][n] = WL[(ksn * 3 + n) * 64 + lane];
            }
        }
        half8 ah, al;
        #pragma unroll
        for (int j = 0; j < 8; ++j) {
            _Float16 h = (_Float16)xv[s][j];
            ah[j] = h;
            al[j] = (_Float16)(xv[s][j] - (float)h);
        }
        acc0 = MFMA32F16(ah, bh[cur][0], acc0);
        acc1 = MFMA32F16(ah, bh[cur][1], acc1);
        acc2 = MFMA32F16(ah, bh[cur][2], acc2);
        acc0 = MFMA32F16(al, bh[cur][0], acc0);
        acc1 = MFMA32F16(al, bh[cur][1], acc1);
        acc2 = MFMA32F16(al, bh[cur][2], acc2);
        acc0 = MFMA32F16(ah, bl[cur][0], acc0);
        acc1 = MFMA32F16(ah, bl[cur][1], acc1);
        acc2 = MFMA32F16(ah, bl[cur][2], acc2);
    }

    // ---- cross-wave combine ----
    *(floatx4*)(smem + ((w * 3 + 0) * 64 + lane) * 4) = acc0;
    *(floatx4*)(smem + ((w * 3 + 1) * 64 + lane) * 4) = acc1;
    *(floatx4*)(smem + ((w * 3 + 2) * 64 + lane) * 4) = acc2;
    __syncthreads();
    floatx4 tot = {0.f, 0.f, 0.f, 0.f};
    if (w < 3) {
        floatx4 t0 = *(const floatx4*)(smem + ((0 * 3 + w) * 64 + lane) * 4);
        floatx4 t1 = *(const floatx4*)(smem + ((1 * 3 + w) * 64 + lane) * 4);
        floatx4 t2 = *(const floatx4*)(smem + ((2 * 3 + w) * 64 + lane) * 4);
        floatx4 t3 = *(const floatx4*)(smem + ((3 * 3 + w) * 64 + lane) * 4);
        tot = t0 + t1 + t2 + t3;
    }
    __syncthreads();   // all cbuf reads done; reuse smem as fragment tiles

    // frag tile region (halves): qh[0,512) ql[512,1024) kh[1024,1536)
    //                            kl[1536,2048) vt[2048,2304)
    _Float16* sh = (_Float16*)smem;
    {   // zero-init 2304 halves = 1152 dwords
        unsigned* zp = (unsigned*)smem;
        for (int i = tid; i < 1152; i += 256) zp[i] = 0u;
    }
    __syncthreads();

    if (w < 3) {
        const int col = m15;
        const int r0  = q8 * 4;
        int msk[4];
        #pragma unroll
        for (int r = 0; r < 4; ++r) msk[r] = mask[rowbase + r0 + r];
        #pragma unroll
        for (int r = 0; r < 4; ++r) {
            const int row = r0 + r;            // row / key slot within tile
            const float val = tot[r];
            if (w == 0) {                      // Q tile
                if (col < 12) {
                    int idx = ((col >> 3) * 16 + row) * 8 + (col & 7);
                    _Float16 h = (_Float16)val;
                    sh[idx]       = h;
                    sh[512 + idx] = (_Float16)(val - (float)h);
                }
            } else if (w == 1) {               // K tile (zero-masked)
                if (col < 12 && msk[r]) {
                    int idx = ((col >> 3) * 16 + row) * 8 + (col & 7);
                    _Float16 h = (_Float16)val;
                    sh[1024 + idx] = h;
                    sh[1536 + idx] = (_Float16)(val - (float)h);
                }
            } else {                           // V^T tile + ones row (l)
                if (col < 12) {
                    if (msk[r]) {
                        int idx = ((row >> 2) * 16 + col) * 4 + (row & 3);
                        sh[2048 + idx] = (_Float16)val;
                    }
                } else if (col == 12) {
                    int idx = ((row >> 2) * 16 + 12) * 4 + (row & 3);
                    sh[2048 + idx] = (_Float16)(msk[r] ? 1.f : 0.f);
                }
            }
        }
    }
    __syncthreads();

    // coalesced tile stores: 64 lanes x 16B (or 8B) each
    const int bb = g >> 7;
    const int tt = g & 127;
    const size_t tb64 = (size_t)(bb * 128 + tt) * 64;
    if (w == 0) {
        ((half8*)qfh)[(size_t)g * 64 + lane] = ((const half8*)(sh))[lane];
        ((half8*)qfl)[(size_t)g * 64 + lane] = ((const half8*)(sh + 512))[lane];
    } else if (w == 1) {
        ((half8*)kfh)[tb64 + lane] = ((const half8*)(sh + 1024))[lane];
        ((half8*)kfl)[tb64 + lane] = ((const half8*)(sh + 1536))[lane];
    } else if (w == 2) {
        ((half4_t*)vtf)[tb64 + lane] = ((const half4_t*)(sh + 2048))[lane];
    }
}

// ---------------- Kernel 2: MFMA flash attention ---------------------------
// grid=512 (two 16-row q-groups per block), block=256 (4 waves stride-4 over
// 128 16-key tiles). Masked keys self-mask (k=0, v=ones=0). Row-max now uses
// 3 INDEPENDENT bpermutes (all-to-all over quads) instead of 2 dependent.
__global__ __launch_bounds__(256)
void attn(const _Float16* __restrict__ qfh, const _Float16* __restrict__ qfl,
          const _Float16* __restrict__ kfh, const _Float16* __restrict__ kfl,
          const _Float16* __restrict__ vtf, float* __restrict__ out)
{
    __shared__ float cm[512];
    __shared__ __align__(16) floatx4 co[512];
    const int tid  = threadIdx.x;
    const int lane = tid & 63;
    const int w    = tid >> 6;
    const int bb   = blockIdx.x & 7;       // XCD-pinned batch
    const int gl   = blockIdx.x >> 3;      // 0..63 within batch
    const int g0   = bb * 128 + gl * 2;
    const int m15  = lane & 15;

    const half8 qh0 = *(const half8*)(qfh + ((size_t)g0 * 64 + lane) * 8);
    const half8 ql0 = *(const half8*)(qfl + ((size_t)g0 * 64 + lane) * 8);
    const half8 qh1 = *(const half8*)(qfh + ((size_t)(g0 + 1) * 64 + lane) * 8);
    const half8 ql1 = *(const half8*)(qfl + ((size_t)(g0 + 1) * 64 + lane) * 8);

    const half8* KH = (const half8*)kfh + (size_t)bb * 128 * 64;
    const half8* KL = (const half8*)kfl + (size_t)bb * 128 * 64;
    const half4_t* VT = (const half4_t*)vtf + (size_t)bb * 128 * 64;

    const int a16 = (lane ^ 16) << 2;
    const int a32 = (lane ^ 32) << 2;
    const int a48 = (lane ^ 48) << 2;

    float m0 = -INFINITY, m1 = -INFINITY;
    floatx4 o0 = {0.f, 0.f, 0.f, 0.f};
    floatx4 o1 = o0;

    int t = w;
    half8 kh = KH[t * 64 + lane];
    half8 kl = KL[t * 64 + lane];
    half4_t va = VT[t * 64 + lane];
    for (; t < 128; t += 4) {
        half8 nkh, nkl; half4_t nva;
        if (t + 4 < 128) {
            nkh = KH[(t + 4) * 64 + lane];
            nkl = KL[(t + 4) * 64 + lane];
            nva = VT[(t + 4) * 64 + lane];
        }
        floatx4 s0 = {0.f, 0.f, 0.f, 0.f};
        floatx4 s1 = s0;
        s0 = MFMA32F16(kh, qh0, s0);
        s1 = MFMA32F16(kh, qh1, s1);
        s0 = MFMA32F16(kl, qh0, s0);
        s1 = MFMA32F16(kl, qh1, s1);
        s0 = MFMA32F16(kh, ql0, s0);
        s1 = MFMA32F16(kh, ql1, s1);
        {
            float pm = fmaxf(fmaxf(s0.x, s0.y), fmaxf(s0.z, s0.w));
            float b1 = bperm(pm, a16);
            float b2 = bperm(pm, a32);
            float b3 = bperm(pm, a48);
            pm = fmaxf(fmaxf(pm, b1), fmaxf(b2, b3));
            float mnew = fmaxf(m0, pm);
            float corr = EXP2F(m0 - mnew);
            o0.x *= corr; o0.y *= corr; o0.z *= corr; o0.w *= corr;
            half4_t pb;
            pb[0] = (_Float16)EXP2F(s0.x - mnew);
            pb[1] = (_Float16)EXP2F(s0.y - mnew);
            pb[2] = (_Float16)EXP2F(s0.z - mnew);
            pb[3] = (_Float16)EXP2F(s0.w - mnew);
            o0 = MFMA16F16(va, pb, o0);
            m0 = mnew;
        }
        {
            float pm = fmaxf(fmaxf(s1.x, s1.y), fmaxf(s1.z, s1.w));
            float b1 = bperm(pm, a16);
            float b2 = bperm(pm, a32);
            float b3 = bperm(pm, a48);
            pm = fmaxf(fmaxf(pm, b1), fmaxf(b2, b3));
            float mnew = fmaxf(m1, pm);
            float corr = EXP2F(m1 - mnew);
            o1.x *= corr; o1.y *= corr; o1.z *= corr; o1.w *= corr;
            half4_t pb;
            pb[0] = (_Float16)EXP2F(s1.x - mnew);
            pb[1] = (_Float16)EXP2F(s1.y - mnew);
            pb[2] = (_Float16)EXP2F(s1.z - mnew);
            pb[3] = (_Float16)EXP2F(s1.w - mnew);
            o1 = MFMA16F16(va, pb, o1);
            m1 = mnew;
        }
        kh = nkh; kl = nkl; va = nva;
    }

    cm[(0 * 4 + w) * 64 + lane] = m0;
    cm[(1 * 4 + w) * 64 + lane] = m1;
    co[(0 * 4 + w) * 64 + lane] = o0;
    co[(1 * 4 + w) * 64 + lane] = o1;
    __syncthreads();
    if (w < 2) {
        const int gi = w;
        float gm = -INFINITY;
        #pragma unroll
        for (int w2 = 0; w2 < 4; ++w2) gm = fmaxf(gm, cm[(gi * 4 + w2) * 64 + lane]);
        floatx4 O = {0.f, 0.f, 0.f, 0.f};
        #pragma unroll
        for (int w2 = 0; w2 < 4; ++w2) {
            float f = EXP2F(cm[(gi * 4 + w2) * 64 + lane] - gm);
            floatx4 ow = co[(gi * 4 + w2) * 64 + lane];
            O.x += ow.x * f; O.y += ow.y * f; O.z += ow.z * f; O.w += ow.w * f;
        }
        float L = bperm(O.x, (48 + m15) << 2);   // l at C row 12
        float inv = 1.0f / L;
        if ((lane >> 4) < 3) {
            float4 ov = make_float4(O.x * inv, O.y * inv, O.z * inv, O.w * inv);
            *(float4*)(out + ((size_t)(g0 + gi) * 16 + m15) * 12 + (lane >> 4) * 4) = ov;
        }
    }
}

extern "C" void kernel_launch(void* const* d_in, const int* in_sizes, int n_in,
                              void* d_out, int out_size, void* d_ws, size_t ws_size,
                              hipStream_t stream) {
    const float* x    = (const float*)d_in[0];
    const int*   mask = (const int*)  d_in[1];
    const float* Wk   = (const float*)d_in[2];   // key_weight
    const float* Wq   = (const float*)d_in[3];   // query_weight
    const float* Wv   = (const float*)d_in[4];   // value_weight
    float* out = (float*)d_out;

    char* base = (char*)d_ws;
    _Float16* qfh = (_Float16*)(base);                    // 1 MB
    _Float16* qfl = (_Float16*)(base + (1u << 20));       // 1 MB
    _Float16* kfh = (_Float16*)(base + (2u << 20));       // 1 MB
    _Float16* kfl = (_Float16*)(base + (3u << 20));       // 1 MB
    _Float16* vtf = (_Float16*)(base + (4u << 20));       // 0.5 MB
    _Float16* wfh = (_Float16*)(base + 4718592);          // 73728 B
    _Float16* wfl = (_Float16*)(base + 4718592 + 73728);  // 73728 B

    prep<<<18, 256, 0, stream>>>(Wq, Wk, Wv, wfh, wfl);
    qkv_mfma<<<1024, 256, 0, stream>>>(x, wfh, wfl, mask, qfh, qfl, kfh, kfl, vtf);
    attn<<<512, 256, 0, stream>>>(qfh, qfl, kfh, kfl, vtf, out);
}

// Round 9
// 117.734 us; speedup vs baseline: 2.7777x; 1.0379x over previous
//
#include <hip/hip_runtime.h>
#include <math.h>

#define QSCALE (0.2886751345948129f * 1.4426950408889634f)  // 1/sqrt(12) * log2(e)

#if __has_builtin(__builtin_amdgcn_exp2f)
#define EXP2F(x) __builtin_amdgcn_exp2f(x)
#else
#define EXP2F(x) exp2f(x)
#endif

typedef __attribute__((ext_vector_type(8))) _Float16 half8;
typedef __attribute__((ext_vector_type(4))) _Float16 half4_t;
typedef __attribute__((ext_vector_type(4))) float floatx4;

#define MFMA32F16(a, b, c) __builtin_amdgcn_mfma_f32_16x16x32_f16((a), (b), (c), 0, 0, 0)
#define MFMA16F16(a, b, c) __builtin_amdgcn_mfma_f32_16x16x16f16((a), (b), (c), 0, 0, 0)

static __device__ inline float bperm(float v, int addr_bytes) {
    return __int_as_float(__builtin_amdgcn_ds_bpermute(addr_bytes, __float_as_int(v)));
}

// ---------------- Kernel P: weight swizzle -> fp16 hi/lo B-frags -----------
__global__ __launch_bounds__(256)
void prep(const float* __restrict__ Wq, const float* __restrict__ Wk,
          const float* __restrict__ Wv, _Float16* __restrict__ wfh,
          _Float16* __restrict__ wfl)
{
    int t = blockIdx.x * 256 + threadIdx.x;
    if (t >= 4608) return;                 // 24 ks * 3 nt * 64 lanes
    int lane = t & 63;
    int nt   = (t >> 6) % 3;
    int ks   = t / 192;
    const float* W = (nt == 0) ? Wq : (nt == 1) ? Wk : Wv;
    const float scale = (nt == 0) ? QSCALE : 1.0f;
    int col = lane & 15;
    int kq  = lane >> 4;
    half8 hi, lo;
    #pragma unroll
    for (int j = 0; j < 8; ++j) {
        int dim = ks * 32 + kq * 8 + j;
        float f = (col < 12) ? W[dim * 12 + col] * scale : 0.0f;
        _Float16 h = (_Float16)f;
        hi[j] = h;
        lo[j] = (_Float16)(f - (float)h);
    }
    size_t off = ((size_t)(ks * 3 + nt) * 64 + lane) * 8;
    *(half8*)(wfh + off) = hi;
    *(half8*)(wfl + off) = lo;
}

// ---------------- Kernel 1: QKV projection, fp16-split MFMA ----------------
// grid=1024, block=256. XCD-ALIGNED remap: g = ((blk&7)<<7)|(blk>>3) so the
// block producing batch bb's K/V fragment tiles runs on XCD bb (same pinning
// as the attn consumer) -> fragments stay dirty in the home L2.
// Main loop + LDS-assembled coalesced epilogue identical to round 8.
__global__ __launch_bounds__(256, 3)
void qkv_mfma(const float* __restrict__ x, const _Float16* __restrict__ wfh,
              const _Float16* __restrict__ wfl, const int* __restrict__ mask,
              _Float16* __restrict__ qfh, _Float16* __restrict__ qfl,
              _Float16* __restrict__ kfh, _Float16* __restrict__ kfl,
              _Float16* __restrict__ vtf)
{
    __shared__ __align__(16) float smem[3072];   // 12 KB: cbuf, then frag tiles
    const int tid  = threadIdx.x;
    const int lane = tid & 63;
    const int w    = tid >> 6;
    const int g    = ((blockIdx.x & 7) << 7) | (blockIdx.x >> 3);  // XCD-aligned
    const int rowbase = g * 16;
    const int m15 = lane & 15;
    const int q8  = lane >> 4;

    const float* xbase = x + (size_t)(rowbase + m15) * 768 + q8 * 8;
    const half8* WH = (const half8*)wfh;
    const half8* WL = (const half8*)wfl;

    // issue ALL x loads up front (independent, 12 in flight)
    float xv[6][8];
    #pragma unroll
    for (int s = 0; s < 6; ++s) {
        const int ks = w * 6 + s;
        *(float4*)(xv[s])     = *(const float4*)(xbase + ks * 32);
        *(float4*)(xv[s] + 4) = *(const float4*)(xbase + ks * 32 + 4);
    }

    floatx4 acc0 = {0.f, 0.f, 0.f, 0.f};
    floatx4 acc1 = acc0, acc2 = acc0;

    half8 bh[2][3], bl[2][3];
    {
        const int ks = w * 6;
        #pragma unroll
        for (int n = 0; n < 3; ++n) {
            bh[0][n] = WH[(ks * 3 + n) * 64 + lane];
            bl[0][n] = WL[(ks * 3 + n) * 64 + lane];
        }
    }

    #pragma unroll
    for (int s = 0; s < 6; ++s) {
        const int cur = s & 1, nxt = cur ^ 1;
        if (s < 5) {
            const int ksn = w * 6 + s + 1;
            #pragma unroll
            for (int n = 0; n < 3; ++n) {
                bh[nxt][n] = WH[(ksn * 3 + n) * 64 + lane];
                bl[nxt][n] = WL[(ksn * 3 + n) * 64 + lane];
            }
        }
        half8 ah, al;
        #pragma unroll
        for (int j = 0; j < 8; ++j) {
            _Float16 h = (_Float16)xv[s][j];
            ah[j] = h;
            al[j] = (_Float16)(xv[s][j] - (float)h);
        }
        acc0 = MFMA32F16(ah, bh[cur][0], acc0);
        acc1 = MFMA32F16(ah, bh[cur][1], acc1);
        acc2 = MFMA32F16(ah, bh[cur][2], acc2);
        acc0 = MFMA32F16(al, bh[cur][0], acc0);
        acc1 = MFMA32F16(al, bh[cur][1], acc1);
        acc2 = MFMA32F16(al, bh[cur][2], acc2);
        acc0 = MFMA32F16(ah, bl[cur][0], acc0);
        acc1 = MFMA32F16(ah, bl[cur][1], acc1);
        acc2 = MFMA32F16(ah, bl[cur][2], acc2);
    }

    // ---- cross-wave combine ----
    *(floatx4*)(smem + ((w * 3 + 0) * 64 + lane) * 4) = acc0;
    *(floatx4*)(smem + ((w * 3 + 1) * 64 + lane) * 4) = acc1;
    *(floatx4*)(smem + ((w * 3 + 2) * 64 + lane) * 4) = acc2;
    __syncthreads();
    floatx4 tot = {0.f, 0.f, 0.f, 0.f};
    if (w < 3) {
        floatx4 t0 = *(const floatx4*)(smem + ((0 * 3 + w) * 64 + lane) * 4);
        floatx4 t1 = *(const floatx4*)(smem + ((1 * 3 + w) * 64 + lane) * 4);
        floatx4 t2 = *(const floatx4*)(smem + ((2 * 3 + w) * 64 + lane) * 4);
        floatx4 t3 = *(const floatx4*)(smem + ((3 * 3 + w) * 64 + lane) * 4);
        tot = t0 + t1 + t2 + t3;
    }
    __syncthreads();   // all cbuf reads done; reuse smem as fragment tiles

    // frag tile region (halves): qh[0,512) ql[512,1024) kh[1024,1536)
    //                            kl[1536,2048) vt[2048,2304)
    _Float16* sh = (_Float16*)smem;
    {   // zero-init 2304 halves = 1152 dwords
        unsigned* zp = (unsigned*)smem;
        for (int i = tid; i < 1152; i += 256) zp[i] = 0u;
    }
    __syncthreads();

    if (w < 3) {
        const int col = m15;
        const int r0  = q8 * 4;
        int msk[4];
        #pragma unroll
        for (int r = 0; r < 4; ++r) msk[r] = mask[rowbase + r0 + r];
        #pragma unroll
        for (int r = 0; r < 4; ++r) {
            const int row = r0 + r;            // row / key slot within tile
            const float val = tot[r];
            if (w == 0) {                      // Q tile
                if (col < 12) {
                    int idx = ((col >> 3) * 16 + row) * 8 + (col & 7);
                    _Float16 h = (_Float16)val;
                    sh[idx]       = h;
                    sh[512 + idx] = (_Float16)(val - (float)h);
                }
            } else if (w == 1) {               // K tile (zero-masked)
                if (col < 12 && msk[r]) {
                    int idx = ((col >> 3) * 16 + row) * 8 + (col & 7);
                    _Float16 h = (_Float16)val;
                    sh[1024 + idx] = h;
                    sh[1536 + idx] = (_Float16)(val - (float)h);
                }
            } else {                           // V^T tile + ones row (l)
                if (col < 12) {
                    if (msk[r]) {
                        int idx = ((row >> 2) * 16 + col) * 4 + (row & 3);
                        sh[2048 + idx] = (_Float16)val;
                    }
                } else if (col == 12) {
                    int idx = ((row >> 2) * 16 + 12) * 4 + (row & 3);
                    sh[2048 + idx] = (_Float16)(msk[r] ? 1.f : 0.f);
                }
            }
        }
    }
    __syncthreads();

    // coalesced tile stores: 64 lanes x 16B (or 8B) each
    const int bb = g >> 7;
    const int tt = g & 127;
    const size_t tb64 = (size_t)(bb * 128 + tt) * 64;
    if (w == 0) {
        ((half8*)qfh)[(size_t)g * 64 + lane] = ((const half8*)(sh))[lane];
        ((half8*)qfl)[(size_t)g * 64 + lane] = ((const half8*)(sh + 512))[lane];
    } else if (w == 1) {
        ((half8*)kfh)[tb64 + lane] = ((const half8*)(sh + 1024))[lane];
        ((half8*)kfl)[tb64 + lane] = ((const half8*)(sh + 1536))[lane];
    } else if (w == 2) {
        ((half4_t*)vtf)[tb64 + lane] = ((const half4_t*)(sh + 2048))[lane];
    }
}

// ---------------- Kernel 2: MFMA flash attention ---------------------------
// grid=256 (FOUR 16-row q-groups per block), block=512 (8 waves stride-8 over
// 128 16-key tiles). Same per-wave exp2/MFMA work as round 8 (64 group-tiles)
// but K/V re-read traffic halved; XCD pinning (blk&7) matches the qkv
// producer remap so fragments are home-L2 resident.
__global__ __launch_bounds__(512)
void attn(const _Float16* __restrict__ qfh, const _Float16* __restrict__ qfl,
          const _Float16* __restrict__ kfh, const _Float16* __restrict__ kfl,
          const _Float16* __restrict__ vtf, float* __restrict__ out)
{
    __shared__ float cm[2048];                    // [gi*8+w][lane]
    __shared__ __align__(16) floatx4 co[2048];    // [gi*8+w][lane]
    const int tid  = threadIdx.x;
    const int lane = tid & 63;
    const int w    = tid >> 6;             // 0..7
    const int bb   = blockIdx.x & 7;       // XCD-pinned batch
    const int gl   = blockIdx.x >> 3;      // 0..31 within batch
    const int g0   = bb * 128 + gl * 4;    // first of 4 q-groups
    const int m15  = lane & 15;

    half8 qh[4], ql[4];
    #pragma unroll
    for (int gi = 0; gi < 4; ++gi) {
        qh[gi] = *(const half8*)(qfh + ((size_t)(g0 + gi) * 64 + lane) * 8);
        ql[gi] = *(const half8*)(qfl + ((size_t)(g0 + gi) * 64 + lane) * 8);
    }

    const half8* KH = (const half8*)kfh + (size_t)bb * 128 * 64;
    const half8* KL = (const half8*)kfl + (size_t)bb * 128 * 64;
    const half4_t* VT = (const half4_t*)vtf + (size_t)bb * 128 * 64;

    const int a16 = (lane ^ 16) << 2;
    const int a32 = (lane ^ 32) << 2;
    const int a48 = (lane ^ 48) << 2;

    float m[4] = {-INFINITY, -INFINITY, -INFINITY, -INFINITY};
    floatx4 o[4];
    #pragma unroll
    for (int gi = 0; gi < 4; ++gi) o[gi] = (floatx4){0.f, 0.f, 0.f, 0.f};

    int t = w;
    half8 kh = KH[t * 64 + lane];
    half8 kl = KL[t * 64 + lane];
    half4_t va = VT[t * 64 + lane];
    for (; t < 128; t += 8) {
        half8 nkh, nkl; half4_t nva;
        if (t + 8 < 128) {
            nkh = KH[(t + 8) * 64 + lane];
            nkl = KL[(t + 8) * 64 + lane];
            nva = VT[(t + 8) * 64 + lane];
        }
        floatx4 s[4];
        #pragma unroll
        for (int gi = 0; gi < 4; ++gi) s[gi] = (floatx4){0.f, 0.f, 0.f, 0.f};
        #pragma unroll
        for (int gi = 0; gi < 4; ++gi) s[gi] = MFMA32F16(kh, qh[gi], s[gi]);
        #pragma unroll
        for (int gi = 0; gi < 4; ++gi) s[gi] = MFMA32F16(kl, qh[gi], s[gi]);
        #pragma unroll
        for (int gi = 0; gi < 4; ++gi) s[gi] = MFMA32F16(kh, ql[gi], s[gi]);
        #pragma unroll
        for (int gi = 0; gi < 4; ++gi) {
            float pm = fmaxf(fmaxf(s[gi].x, s[gi].y), fmaxf(s[gi].z, s[gi].w));
            float b1 = bperm(pm, a16);
            float b2 = bperm(pm, a32);
            float b3 = bperm(pm, a48);
            pm = fmaxf(fmaxf(pm, b1), fmaxf(b2, b3));
            float mnew = fmaxf(m[gi], pm);
            float corr = EXP2F(m[gi] - mnew);
            o[gi].x *= corr; o[gi].y *= corr; o[gi].z *= corr; o[gi].w *= corr;
            half4_t pb;
            pb[0] = (_Float16)EXP2F(s[gi].x - mnew);
            pb[1] = (_Float16)EXP2F(s[gi].y - mnew);
            pb[2] = (_Float16)EXP2F(s[gi].z - mnew);
            pb[3] = (_Float16)EXP2F(s[gi].w - mnew);
            o[gi] = MFMA16F16(va, pb, o[gi]);
            m[gi] = mnew;
        }
        kh = nkh; kl = nkl; va = nva;
    }

    #pragma unroll
    for (int gi = 0; gi < 4; ++gi) {
        cm[(gi * 8 + w) * 64 + lane] = m[gi];
        co[(gi * 8 + w) * 64 + lane] = o[gi];
    }
    __syncthreads();
    if (w < 4) {
        const int gi = w;
        float gm = -INFINITY;
        #pragma unroll
        for (int w2 = 0; w2 < 8; ++w2) gm = fmaxf(gm, cm[(gi * 8 + w2) * 64 + lane]);
        floatx4 O = {0.f, 0.f, 0.f, 0.f};
        #pragma unroll
        for (int w2 = 0; w2 < 8; ++w2) {
            float f = EXP2F(cm[(gi * 8 + w2) * 64 + lane] - gm);
            floatx4 ow = co[(gi * 8 + w2) * 64 + lane];
            O.x += ow.x * f; O.y += ow.y * f; O.z += ow.z * f; O.w += ow.w * f;
        }
        float L = bperm(O.x, (48 + m15) << 2);   // l at C row 12
        float inv = 1.0f / L;
        if ((lane >> 4) < 3) {
            float4 ov = make_float4(O.x * inv, O.y * inv, O.z * inv, O.w * inv);
            *(float4*)(out + ((size_t)(g0 + gi) * 16 + m15) * 12 + (lane >> 4) * 4) = ov;
        }
    }
}

extern "C" void kernel_launch(void* const* d_in, const int* in_sizes, int n_in,
                              void* d_out, int out_size, void* d_ws, size_t ws_size,
                              hipStream_t stream) {
    const float* x    = (const float*)d_in[0];
    const int*   mask = (const int*)  d_in[1];
    const float* Wk   = (const float*)d_in[2];   // key_weight
    const float* Wq   = (const float*)d_in[3];   // query_weight
    const float* Wv   = (const float*)d_in[4];   // value_weight
    float* out = (float*)d_out;

    char* base = (char*)d_ws;
    _Float16* qfh = (_Float16*)(base);                    // 1 MB
    _Float16* qfl = (_Float16*)(base + (1u << 20));       // 1 MB
    _Float16* kfh = (_Float16*)(base + (2u << 20));       // 1 MB
    _Float16* kfl = (_Float16*)(base + (3u << 20));       // 1 MB
    _Float16* vtf = (_Float16*)(base + (4u << 20));       // 0.5 MB
    _Float16* wfh = (_Float16*)(base + 4718592);          // 73728 B
    _Float16* wfl = (_Float16*)(base + 4718592 + 73728);  // 73728 B

    prep<<<18, 256, 0, stream>>>(Wq, Wk, Wv, wfh, wfl);
    qkv_mfma<<<1024, 256, 0, stream>>>(x, wfh, wfl, mask, qfh, qfl, kfh, kfl, vtf);
    attn<<<256, 512, 0, stream>>>(qfh, qfl, kfh, kfl, vtf, out);
}